// Round 5
// baseline (1263.322 us; speedup 1.0000x reference)
//
#include <hip/hip_runtime.h>
#include <hip/hip_bf16.h>

#define BATCH 4
#define SEQ   512
#define CH    512
#define NTOK  2048      // BATCH*SEQ
#define FF    2048      // I
#define NEXP  32
#define TOPK  2
#define VOCAB 32000
#define NHEAD 8
#define HDIM  64
#define EPSF  1e-5f

typedef __attribute__((ext_vector_type(8))) short short8v;   // 8 bf16 (4 VGPR)
typedef __attribute__((ext_vector_type(4))) float f32x4;     // MFMA acc

__device__ __forceinline__ unsigned short bf16r(float f) {   // RNE fp32->bf16
  unsigned int u = __float_as_uint(f);
  u = (u + 0x7FFFu + ((u >> 16) & 1u)) >> 16;
  return (unsigned short)u;
}

__device__ __forceinline__ float block_reduce_sum(float v, float* sbuf) {
  #pragma unroll
  for (int off = 32; off > 0; off >>= 1) v += __shfl_down(v, off, 64);
  const int lane = threadIdx.x & 63, wid = threadIdx.x >> 6;
  __syncthreads();
  if (lane == 0) sbuf[wid] = v;
  __syncthreads();
  return sbuf[0] + sbuf[1] + sbuf[2] + sbuf[3];
}

__device__ __forceinline__ float gelu_exact(float v) {
  return 0.5f * v * (1.f + erff(v * 0.70710678118654752f));
}

// ============ transpose + fp32->bf16 convert: out[c][r] = in[r][c] ============
// in [R][C] fp32 (+z*R*C), out [C][R] bf16 (+z*R*C). grid (C/64, R/64, Z)
__global__ __launch_bounds__(256) void transpose_cvt_kernel(
    const float* __restrict__ in, unsigned short* __restrict__ out, int R, int C) {
  __shared__ float T[64][65];
  const size_t zoff = (size_t)blockIdx.z * R * C;
  in += zoff; out += zoff;
  const int r0 = blockIdx.y << 6;
  const int c0 = blockIdx.x << 6;
  const int t = threadIdx.x;
  const int lr = t >> 4;            // 0..15
  const int lc = (t & 15) << 2;     // 0..60
  #pragma unroll
  for (int rr = 0; rr < 64; rr += 16) {
    const float4 v = *(const float4*)(in + (size_t)(r0 + lr + rr) * C + c0 + lc);
    T[lr + rr][lc + 0] = v.x; T[lr + rr][lc + 1] = v.y;
    T[lr + rr][lc + 2] = v.z; T[lr + rr][lc + 3] = v.w;
  }
  __syncthreads();
  const int oc = t >> 2;            // 0..63 output row (= input col)
  const int rs = (t & 3) << 4;      // 16-element segment along r
  unsigned int pk[8];
  #pragma unroll
  for (int j = 0; j < 8; ++j) {
    const float a = T[rs + 2 * j][oc];
    const float b = T[rs + 2 * j + 1][oc];
    pk[j] = (unsigned int)bf16r(a) | ((unsigned int)bf16r(b) << 16);
  }
  unsigned short* op = out + (size_t)(c0 + oc) * R + r0 + rs;
  *(uint4*)(op)     = make_uint4(pk[0], pk[1], pk[2], pk[3]);
  *(uint4*)(op + 8) = make_uint4(pk[4], pk[5], pk[6], pk[7]);
}

// ============ embed + LN1 -> h fp32, x fp32 ============
__global__ __launch_bounds__(256) void embed_ln_kernel(
    const int* __restrict__ ids, const float* __restrict__ emb,
    const float* __restrict__ g, const float* __restrict__ b,
    float* __restrict__ h, float* __restrict__ x) {
  __shared__ float sbuf[4];
  const int n = blockIdx.x, t = threadIdx.x;
  const float2 v = *(const float2*)(emb + (size_t)ids[n] * CH + 2 * t);
  *(float2*)(h + (size_t)n * CH + 2 * t) = v;
  const float mu = block_reduce_sum(v.x + v.y, sbuf) * (1.f / CH);
  const float d0 = v.x - mu, d1 = v.y - mu;
  const float var = block_reduce_sum(d0 * d0 + d1 * d1, sbuf) * (1.f / CH);
  const float rstd = rsqrtf(var + EPSF);
  const float2 gg = *(const float2*)(g + 2 * t);
  const float2 bb = *(const float2*)(b + 2 * t);
  *(float2*)(x + (size_t)n * CH + 2 * t) =
      make_float2(d0 * rstd * gg.x + bb.x, d1 * rstd * gg.y + bb.y);
}

// ============ LN2 -> x2 fp32 (output) + x2 bf16 (for MoE fc1) ============
__global__ __launch_bounds__(256) void ln2_kernel(
    const float* __restrict__ in, const float* __restrict__ g,
    const float* __restrict__ b, float* __restrict__ outf,
    unsigned short* __restrict__ outbf) {
  __shared__ float sbuf[4];
  const int n = blockIdx.x, t = threadIdx.x;
  const float2 v = *(const float2*)(in + (size_t)n * CH + 2 * t);
  const float mu = block_reduce_sum(v.x + v.y, sbuf) * (1.f / CH);
  const float d0 = v.x - mu, d1 = v.y - mu;
  const float var = block_reduce_sum(d0 * d0 + d1 * d1, sbuf) * (1.f / CH);
  const float rstd = rsqrtf(var + EPSF);
  const float2 gg = *(const float2*)(g + 2 * t);
  const float2 bb = *(const float2*)(b + 2 * t);
  const float o0 = d0 * rstd * gg.x + bb.x;
  const float o1 = d1 * rstd * gg.y + bb.y;
  *(float2*)(outf + (size_t)n * CH + 2 * t) = make_float2(o0, o1);
  ((unsigned int*)outbf)[(size_t)n * (CH / 2) + t] =
      (unsigned int)bf16r(o0) | ((unsigned int)bf16r(o1) << 16);
}

// ============ fp32 GEMM (exact routing path): C = A[M,K] @ B[K,N] (+Res) ======
// tile 64x128, BK=32, 256 threads, 4x8 micro-tile
__global__ __launch_bounds__(256) void gemm_f32_kernel(
    const float* __restrict__ A, const float* __restrict__ B,
    const float* __restrict__ Res, float* __restrict__ C,
    int M, int N, int K) {
  __shared__ float As[32][68];
  __shared__ float Bs[32][132];
  const int m0 = blockIdx.y << 6;
  const int n0 = blockIdx.x << 7;
  const int t  = threadIdx.x;
  const int tm = t >> 4;
  const int tn = t & 15;
  float acc[4][8];
  #pragma unroll
  for (int i = 0; i < 4; ++i)
    #pragma unroll
    for (int j = 0; j < 8; ++j) acc[i][j] = 0.f;

  const int ar = t >> 3;          // 0..31
  const int ac = (t & 7) << 2;    // 0..28
  const int bk = t >> 3;          // 0..31
  const int bn = (t & 7) << 4;    // 0..112

  for (int kt = 0; kt < K; kt += 32) {
    #pragma unroll
    for (int rr = 0; rr < 64; rr += 32) {
      float4 a = *(const float4*)(A + (size_t)(m0 + ar + rr) * K + kt + ac);
      As[ac + 0][ar + rr] = a.x; As[ac + 1][ar + rr] = a.y;
      As[ac + 2][ar + rr] = a.z; As[ac + 3][ar + rr] = a.w;
    }
    const float* bp = B + (size_t)(kt + bk) * N + n0 + bn;
    #pragma unroll
    for (int j = 0; j < 16; j += 4)
      *(float4*)&Bs[bk][bn + j] = *(const float4*)(bp + j);
    __syncthreads();
    #pragma unroll
    for (int k = 0; k < 32; ++k) {
      const float4 av = *(const float4*)&As[k][tm << 2];
      const float4 bl = *(const float4*)&Bs[k][tn << 2];
      const float4 bh = *(const float4*)&Bs[k][64 + (tn << 2)];
      const float a_[4] = {av.x, av.y, av.z, av.w};
      const float b_[8] = {bl.x, bl.y, bl.z, bl.w, bh.x, bh.y, bh.z, bh.w};
      #pragma unroll
      for (int i = 0; i < 4; ++i)
        #pragma unroll
        for (int j = 0; j < 8; ++j)
          acc[i][j] = fmaf(a_[i], b_[j], acc[i][j]);
    }
    __syncthreads();
  }
  #pragma unroll
  for (int i = 0; i < 4; ++i) {
    const int row = m0 + (tm << 2) + i;
    float* cp = C + (size_t)row * N + n0 + (tn << 2);
    float4 lo = make_float4(acc[i][0], acc[i][1], acc[i][2], acc[i][3]);
    float4 hi = make_float4(acc[i][4], acc[i][5], acc[i][6], acc[i][7]);
    if (Res) {
      const float* rp = Res + (size_t)row * N + n0 + (tn << 2);
      const float4 r0 = *(const float4*)rp;
      const float4 r1 = *(const float4*)(rp + 64);
      lo.x += r0.x; lo.y += r0.y; lo.z += r0.z; lo.w += r0.w;
      hi.x += r1.x; hi.y += r1.y; hi.z += r1.z; hi.w += r1.w;
    }
    *(float4*)cp        = lo;
    *(float4*)(cp + 64) = hi;
  }
}

// ============ bf16 MFMA GEMM: C[M,N] fp32 = A[M,K]bf16 @ BT[N,K]bf16 ====
// tile 128x128, BK=64, 4 waves (2x2), 4x4 frags of 16x16x32. SWZ: XCD remap.
template <int SWZ>
__global__ __launch_bounds__(256) void gemm_bf16_kernel(
    const unsigned short* __restrict__ A, const unsigned short* __restrict__ BT,
    float* __restrict__ C, int M, int N, int K) {
  int bx = blockIdx.x, by = blockIdx.y;
  if (SWZ) {
    const int gx = gridDim.x;
    const int nb = gx * gridDim.y;
    int bid = by * gx + bx;
    bid = (bid & 7) * (nb >> 3) + (bid >> 3);   // bijective when nb % 8 == 0
    bx = bid % gx;
    by = bid / gx;
  }
  __shared__ unsigned short As[128][72];
  __shared__ unsigned short Bs[128][72];
  const int m0 = by << 7;
  const int n0 = bx << 7;
  const int t  = threadIdx.x;
  const int w  = t >> 6;
  const int l  = t & 63;
  const int wm = (w >> 1) << 6;
  const int wn = (w & 1) << 6;
  const int fr = l & 15;
  const int fg = l >> 4;
  f32x4 acc[4][4];
  #pragma unroll
  for (int i = 0; i < 4; ++i)
    #pragma unroll
    for (int j = 0; j < 4; ++j) acc[i][j] = (f32x4){0.f, 0.f, 0.f, 0.f};

  const int sr = t >> 1;              // 0..127 staging row
  const int sc = (t & 1) << 5;        // 0 or 32 (bf16 cols)
  const unsigned short* ap = A  + (size_t)(m0 + sr) * K + sc;
  const unsigned short* bp = BT + (size_t)(n0 + sr) * K + sc;

  for (int kt = 0; kt < K; kt += 64) {
    #pragma unroll
    for (int j = 0; j < 4; ++j) {
      *(uint4*)&As[sr][sc + (j << 3)] = *(const uint4*)(ap + kt + (j << 3));
      *(uint4*)&Bs[sr][sc + (j << 3)] = *(const uint4*)(bp + kt + (j << 3));
    }
    __syncthreads();
    #pragma unroll
    for (int kk = 0; kk < 64; kk += 32) {
      short8v afr[4], bfr[4];
      #pragma unroll
      for (int i = 0; i < 4; ++i)
        afr[i] = *(const short8v*)&As[wm + (i << 4) + fr][kk + (fg << 3)];
      #pragma unroll
      for (int j = 0; j < 4; ++j)
        bfr[j] = *(const short8v*)&Bs[wn + (j << 4) + fr][kk + (fg << 3)];
      #pragma unroll
      for (int i = 0; i < 4; ++i)
        #pragma unroll
        for (int j = 0; j < 4; ++j)
          acc[i][j] = __builtin_amdgcn_mfma_f32_16x16x32_bf16(afr[i], bfr[j], acc[i][j], 0, 0, 0);
    }
    __syncthreads();
  }
  #pragma unroll
  for (int i = 0; i < 4; ++i) {
    #pragma unroll
    for (int j = 0; j < 4; ++j) {
      const int col = n0 + wn + (j << 4) + fr;
      const int rowb = m0 + wm + (i << 4) + (fg << 2);
      #pragma unroll
      for (int r = 0; r < 4; ++r)
        C[(size_t)(rowb + r) * N + col] = acc[i][j][r];
    }
  }
}

// ============ flash attention fp32 (exact routing path), separate q/k/v ======
__global__ __launch_bounds__(256) void attn_kernel(
    const float* __restrict__ q, const float* __restrict__ kbuf,
    const float* __restrict__ vbuf, float* __restrict__ ao) {
  __shared__ float Ks[64][68];
  __shared__ float Vs[64][68];
  __shared__ float Sx[64][65];
  const int bh = blockIdx.x;
  const int qt = blockIdx.y;
  const int b  = bh >> 3;
  const int hh = bh & 7;
  const int t  = threadIdx.x;
  const int qi   = t >> 2;
  const int part = t & 3;
  const int qglob = (qt << 6) + qi;
  const size_t qoff = (size_t)(b * SEQ + qglob) * CH + hh * HDIM + (part << 4);
  float qreg[16];
  #pragma unroll
  for (int j = 0; j < 16; j += 4) {
    const float4 v4 = *(const float4*)(q + qoff + j);
    qreg[j] = v4.x; qreg[j + 1] = v4.y; qreg[j + 2] = v4.z; qreg[j + 3] = v4.w;
  }
  float o[16];
  #pragma unroll
  for (int j = 0; j < 16; ++j) o[j] = 0.f;
  float m = -3.0e38f, l = 0.f;
  const int lr = t >> 2;
  const int lc = (t & 3) << 4;
  for (int kt = 0; kt <= qt; ++kt) {
    const size_t base = (size_t)(b * SEQ + (kt << 6) + lr) * CH + hh * HDIM + lc;
    #pragma unroll
    for (int j = 0; j < 16; j += 4) {
      *(float4*)&Ks[lr][lc + j] = *(const float4*)(kbuf + base + j);
      *(float4*)&Vs[lr][lc + j] = *(const float4*)(vbuf + base + j);
    }
    __syncthreads();
    float sloc[16];
    float tmax = -3.0e38f;
    for (int kk = 0; kk < 64; ++kk) {
      float p = 0.f;
      const float* kr = &Ks[kk][part << 4];
      #pragma unroll
      for (int j = 0; j < 16; ++j) p = fmaf(qreg[j], kr[j], p);
      p += __shfl_xor(p, 1, 64);
      p += __shfl_xor(p, 2, 64);
      p *= 0.125f;
      if (((kt << 6) + kk) > qglob) p = -3.0e38f;
      tmax = fmaxf(tmax, p);
      if ((kk & 3) == part) sloc[kk >> 2] = p;
    }
    const float mnew = fmaxf(m, tmax);
    const float corr = expf(m - mnew);
    float lsum = 0.f;
    #pragma unroll
    for (int j = 0; j < 16; ++j) {
      const float pe = expf(sloc[j] - mnew);
      lsum += pe;
      Sx[qi][(j << 2) + part] = pe;
    }
    lsum += __shfl_xor(lsum, 1, 64);
    lsum += __shfl_xor(lsum, 2, 64);
    l = l * corr + lsum;
    m = mnew;
    #pragma unroll
    for (int j = 0; j < 16; ++j) o[j] *= corr;
    __syncthreads();
    for (int kk = 0; kk < 64; ++kk) {
      const float pv = Sx[qi][kk];
      const float* vr = &Vs[kk][part << 4];
      #pragma unroll
      for (int j = 0; j < 16; ++j) o[j] = fmaf(pv, vr[j], o[j]);
    }
    __syncthreads();
  }
  const float inv = 1.f / l;
  #pragma unroll
  for (int j = 0; j < 16; j += 4)
    *(float4*)(ao + qoff + j) =
        make_float4(o[j] * inv, o[j + 1] * inv, o[j + 2] * inv, o[j + 3] * inv);
}

// ============ router + top-2 + bucketing (fp32, exact) ============
__global__ __launch_bounds__(256) void router_kernel(
    const float* __restrict__ x2, const float* __restrict__ gate,
    float* __restrict__ rl, float* __restrict__ rw, int* __restrict__ sel,
    int* __restrict__ counts, int* __restrict__ lists) {
  __shared__ float xrow[CH];
  __shared__ float lg[NEXP];
  const int n = blockIdx.x;
  const int t = threadIdx.x;
  xrow[t]       = x2[(size_t)n * CH + t];
  xrow[t + 256] = x2[(size_t)n * CH + t + 256];
  __syncthreads();
  const int e = t >> 3, i = t & 7;
  float p = 0.f;
  const float* gp = gate + e;
  for (int c = i * 64; c < i * 64 + 64; ++c) p = fmaf(xrow[c], gp[(size_t)c * NEXP], p);
  p += __shfl_xor(p, 1, 64);
  p += __shfl_xor(p, 2, 64);
  p += __shfl_xor(p, 4, 64);
  if (i == 0) { lg[e] = p; rl[(size_t)n * NEXP + e] = p; }
  __syncthreads();
  if (t == 0) {
    int i0 = 0; float v0 = lg[0];
    for (int j = 1; j < NEXP; ++j) if (lg[j] > v0) { v0 = lg[j]; i0 = j; }
    int i1 = (i0 == 0) ? 1 : 0; float v1 = lg[i1];
    for (int j = 0; j < NEXP; ++j) {
      if (j == i0 || j == i1) continue;
      if (lg[j] > v1) { v1 = lg[j]; i1 = j; }
    }
    const float ex = expf(v1 - v0);
    const float den = 1.f + ex;
    rw[n * 2]     = 1.f / den;
    rw[n * 2 + 1] = ex / den;
    sel[n * 2]     = i0;
    sel[n * 2 + 1] = i1;
    const int s0 = atomicAdd(&counts[i0], 1);
    lists[i0 * NTOK + s0] = n * 2;
    const int s1 = atomicAdd(&counts[i1], 1);
    lists[i1 * NTOK + s1] = n * 2 + 1;
  }
}

// ============ MoE fc1: hidden[pid] = bf16(gelu(x2 @ w1[e])) ============
// tile 64 tok x 128 ff, BK=64. grid (FF/128, NEXP, NTOK/64) with early-exit
__global__ __launch_bounds__(256) void moe_fc1_bf16(
    const unsigned short* __restrict__ x2bf, const unsigned short* __restrict__ w1T,
    const int* __restrict__ counts, const int* __restrict__ lists,
    unsigned short* __restrict__ hidden) {
  const int e  = blockIdx.y;
  const int nt = counts[e];
  const int mt = blockIdx.z << 6;
  if (mt >= nt) return;
  const int i0 = blockIdx.x << 7;
  __shared__ unsigned short As[64][72];
  __shared__ unsigned short Bs[128][72];
  __shared__ int ls[64];
  const int* lst = lists + e * NTOK;
  const int t = threadIdx.x;
  if (t < 64) ls[t] = (mt + t < nt) ? lst[mt + t] : -1;
  __syncthreads();
  const int w  = t >> 6, l = t & 63;
  const int wm = (w >> 1) << 5;       // 0 or 32
  const int wn = (w & 1) << 6;        // 0 or 64
  const int fr = l & 15, fg = l >> 4;
  f32x4 acc[2][4];
  #pragma unroll
  for (int i = 0; i < 2; ++i)
    #pragma unroll
    for (int j = 0; j < 4; ++j) acc[i][j] = (f32x4){0.f, 0.f, 0.f, 0.f};

  const int arow = t >> 2, akc = (t & 3) << 4;      // A: 64 rows x 32B
  const int brow = t >> 1, bkc = (t & 1) << 5;      // B: 128 rows x 64B
  const int apid = ls[arow];
  const unsigned short* arp = (apid >= 0) ? (x2bf + (size_t)(apid >> 1) * CH) : nullptr;
  const unsigned short* brp = w1T + (size_t)e * FF * CH + (size_t)(i0 + brow) * CH;

  for (int kt = 0; kt < CH; kt += 64) {
    if (arp) {
      *(uint4*)&As[arow][akc + 0] = *(const uint4*)(arp + kt + akc + 0);
      *(uint4*)&As[arow][akc + 8] = *(const uint4*)(arp + kt + akc + 8);
    } else {
      *(uint4*)&As[arow][akc + 0] = make_uint4(0, 0, 0, 0);
      *(uint4*)&As[arow][akc + 8] = make_uint4(0, 0, 0, 0);
    }
    #pragma unroll
    for (int j = 0; j < 4; ++j)
      *(uint4*)&Bs[brow][bkc + (j << 3)] = *(const uint4*)(brp + kt + bkc + (j << 3));
    __syncthreads();
    #pragma unroll
    for (int kk = 0; kk < 64; kk += 32) {
      short8v afr[2], bfr[4];
      #pragma unroll
      for (int i = 0; i < 2; ++i)
        afr[i] = *(const short8v*)&As[wm + (i << 4) + fr][kk + (fg << 3)];
      #pragma unroll
      for (int j = 0; j < 4; ++j)
        bfr[j] = *(const short8v*)&Bs[wn + (j << 4) + fr][kk + (fg << 3)];
      #pragma unroll
      for (int i = 0; i < 2; ++i)
        #pragma unroll
        for (int j = 0; j < 4; ++j)
          acc[i][j] = __builtin_amdgcn_mfma_f32_16x16x32_bf16(afr[i], bfr[j], acc[i][j], 0, 0, 0);
    }
    __syncthreads();
  }
  #pragma unroll
  for (int i = 0; i < 2; ++i) {
    #pragma unroll
    for (int r = 0; r < 4; ++r) {
      const int lrow = wm + (i << 4) + (fg << 2) + r;
      const int pid = ls[lrow];
      if (pid < 0) continue;
      unsigned short* hp = hidden + (size_t)pid * FF + i0 + wn + fr;
      #pragma unroll
      for (int j = 0; j < 4; ++j)
        hp[j << 4] = bf16r(gelu_exact(acc[i][j][r]));
    }
  }
}

// ============ MoE fc2: fe[n,e] = hidden[pid] @ w2[e] (fp32 out) ============
// tile 64 tok x 128 ch, BK=64, K=FF. grid (CH/128, NEXP, NTOK/64) early-exit
__global__ __launch_bounds__(256) void moe_fc2_bf16(
    const unsigned short* __restrict__ hidden, const unsigned short* __restrict__ w2T,
    const int* __restrict__ counts, const int* __restrict__ lists,
    float* __restrict__ fe) {
  const int e  = blockIdx.y;
  const int nt = counts[e];
  const int mt = blockIdx.z << 6;
  if (mt >= nt) return;
  const int c0 = blockIdx.x << 7;
  __shared__ unsigned short As[64][72];
  __shared__ unsigned short Bs[128][72];
  __shared__ int ls[64];
  const int* lst = lists + e * NTOK;
  const int t = threadIdx.x;
  if (t < 64) ls[t] = (mt + t < nt) ? lst[mt + t] : -1;
  __syncthreads();
  const int w  = t >> 6, l = t & 63;
  const int wm = (w >> 1) << 5;
  const int wn = (w & 1) << 6;
  const int fr = l & 15, fg = l >> 4;
  f32x4 acc[2][4];
  #pragma unroll
  for (int i = 0; i < 2; ++i)
    #pragma unroll
    for (int j = 0; j < 4; ++j) acc[i][j] = (f32x4){0.f, 0.f, 0.f, 0.f};

  const int arow = t >> 2, akc = (t & 3) << 4;
  const int brow = t >> 1, bkc = (t & 1) << 5;
  const int apid = ls[arow];
  const unsigned short* arp = (apid >= 0) ? (hidden + (size_t)apid * FF) : nullptr;
  const unsigned short* brp = w2T + (size_t)e * CH * FF + (size_t)(c0 + brow) * FF;

  for (int kt = 0; kt < FF; kt += 64) {
    if (arp) {
      *(uint4*)&As[arow][akc + 0] = *(const uint4*)(arp + kt + akc + 0);
      *(uint4*)&As[arow][akc + 8] = *(const uint4*)(arp + kt + akc + 8);
    } else {
      *(uint4*)&As[arow][akc + 0] = make_uint4(0, 0, 0, 0);
      *(uint4*)&As[arow][akc + 8] = make_uint4(0, 0, 0, 0);
    }
    #pragma unroll
    for (int j = 0; j < 4; ++j)
      *(uint4*)&Bs[brow][bkc + (j << 3)] = *(const uint4*)(brp + kt + bkc + (j << 3));
    __syncthreads();
    #pragma unroll
    for (int kk = 0; kk < 64; kk += 32) {
      short8v afr[2], bfr[4];
      #pragma unroll
      for (int i = 0; i < 2; ++i)
        afr[i] = *(const short8v*)&As[wm + (i << 4) + fr][kk + (fg << 3)];
      #pragma unroll
      for (int j = 0; j < 4; ++j)
        bfr[j] = *(const short8v*)&Bs[wn + (j << 4) + fr][kk + (fg << 3)];
      #pragma unroll
      for (int i = 0; i < 2; ++i)
        #pragma unroll
        for (int j = 0; j < 4; ++j)
          acc[i][j] = __builtin_amdgcn_mfma_f32_16x16x32_bf16(afr[i], bfr[j], acc[i][j], 0, 0, 0);
    }
    __syncthreads();
  }
  #pragma unroll
  for (int i = 0; i < 2; ++i) {
    #pragma unroll
    for (int r = 0; r < 4; ++r) {
      const int lrow = wm + (i << 4) + (fg << 2) + r;
      const int pid = ls[lrow];
      if (pid < 0) continue;
      const int n = pid >> 1;
      float* op = fe + ((size_t)n * NEXP + e) * CH + c0 + wn + fr;
      #pragma unroll
      for (int j = 0; j < 4; ++j)
        op[j << 4] = acc[i][j][r];
    }
  }
}

// ============ combine: hf_bf = bf16(h2 + rw0*fe[s0] + rw1*fe[s1]) ============
__global__ __launch_bounds__(256) void combine_kernel(
    const float* __restrict__ h2, const float* __restrict__ fe,
    const float* __restrict__ rw, const int* __restrict__ sel,
    unsigned short* __restrict__ hfbf) {
  const int idx = blockIdx.x * 256 + threadIdx.x;   // NTOK*CH/4
  const int n = idx >> 7;
  const int c = (idx & 127) << 2;
  const float w0 = rw[n * 2], w1 = rw[n * 2 + 1];
  const int s0 = sel[n * 2], s1 = sel[n * 2 + 1];
  const float* base = fe + (size_t)n * NEXP * CH + c;
  const float4 f0 = *(const float4*)(base + (size_t)s0 * CH);
  const float4 f1 = *(const float4*)(base + (size_t)s1 * CH);
  const float4 a  = *(const float4*)(h2 + (size_t)n * CH + c);
  const float ox = a.x + w0 * f0.x + w1 * f1.x;
  const float oy = a.y + w0 * f0.y + w1 * f1.y;
  const float oz = a.z + w0 * f0.z + w1 * f1.z;
  const float ow = a.w + w0 * f0.w + w1 * f1.w;
  uint2 pk;
  pk.x = (unsigned int)bf16r(ox) | ((unsigned int)bf16r(oy) << 16);
  pk.y = (unsigned int)bf16r(oz) | ((unsigned int)bf16r(ow) << 16);
  *(uint2*)(hfbf + (size_t)n * CH + c) = pk;
}

// ============ launch ============
extern "C" void kernel_launch(void* const* d_in, const int* in_sizes, int n_in,
                              void* d_out, int out_size, void* d_ws, size_t ws_size,
                              hipStream_t stream) {
  const int*   ids  = (const int*)d_in[0];
  const float* emb  = (const float*)d_in[1];
  const float* wq   = (const float*)d_in[2];
  const float* wk   = (const float*)d_in[3];
  const float* wv   = (const float*)d_in[4];
  const float* wo   = (const float*)d_in[5];
  const float* gate = (const float*)d_in[6];
  const float* w1   = (const float*)d_in[7];
  const float* w2   = (const float*)d_in[8];
  const float* g1   = (const float*)d_in[9];
  const float* b1   = (const float*)d_in[10];
  const float* g2   = (const float*)d_in[11];
  const float* b2   = (const float*)d_in[12];
  const float* lmh  = (const float*)d_in[13];

  float* out        = (float*)d_out;
  float* out_logits = out;                                   // 65,536,000 f
  float* out_fe     = out_logits + (size_t)NTOK * VOCAB;     // 33,554,432 f
  float* out_rl     = out_fe + (size_t)NTOK * NEXP * CH;     // 65,536 f
  float* out_x2     = out_rl + (size_t)NTOK * NEXP;          // 1,048,576 f

  // --- scratch inside out_logits region: all DEAD before final GEMM writes ---
  unsigned short* w1T    = (unsigned short*)(out_logits);                // [0, 16,777,216) f
  unsigned short* w2T    = (unsigned short*)(out_logits + 16777216);     // [.., 33,554,432)
  unsigned short* hidden = (unsigned short*)(out_logits + 33554432);     // [.., 37,748,736)
  float*          x      = out_logits + 37748736;                        // [.., 38,797,312)
  float*          qb     = out_logits + 38797312;                        // [.., 39,845,888)
  float*          kb     = out_logits + 39845888;                        // [.., 40,894,464)
  float*          vb     = out_logits + 40894464;                        // [.., 41,943,040)
  float*          ao     = out_logits + 41943040;                        // [.., 42,991,616)
  float*          h      = out_logits + 42991616;                        // [.., 44,040,192)
  float*          h2     = out_logits + 44040192;                        // [.., 45,088,768)
  unsigned short* x2_bf  = (unsigned short*)(out_logits + 45088768);     // [.., 45,613,056)
  // ends at 45,613,056 f < 65,536,000 f

  // --- ws: ONLY what the final GEMM reads + bucketing smalls (~35.2 MB) ---
  float* ws    = (float*)d_ws;
  unsigned short* lmhT  = (unsigned short*)ws;               // 16,384,000 bf16 = 8,192,000 f
  unsigned short* hf_bf = (unsigned short*)(ws + 8192000);   // 1,048,576 bf16 = 524,288 f
  float* rw    = ws + 8716288;
  int*   sel   = (int*)(rw + NTOK * TOPK);
  int*   counts= sel + NTOK * TOPK;
  int*   lists = counts + 64;                                // NEXP*NTOK ints

  hipMemsetAsync(counts, 0, NEXP * sizeof(int), stream);
  hipMemsetAsync(out_fe, 0, (size_t)NTOK * NEXP * CH * sizeof(float), stream);

  // weight transposes (fp32 -> bf16 [N][K]) — only MoE + lm_head need them now
  transpose_cvt_kernel<<<dim3(500, 8, 1),   256, 0, stream>>>(lmh, lmhT, CH, VOCAB);
  transpose_cvt_kernel<<<dim3(32, 8, NEXP), 256, 0, stream>>>(w1, w1T, CH, FF);
  transpose_cvt_kernel<<<dim3(8, 32, NEXP), 256, 0, stream>>>(w2, w2T, FF, CH);

  embed_ln_kernel<<<NTOK, 256, 0, stream>>>(ids, emb, g1, b1, h, x);

  // QKV projections (fp32 exact — routing path)
  gemm_f32_kernel<<<dim3(CH / 128, NTOK / 64), 256, 0, stream>>>(x, wq, nullptr, qb, NTOK, CH, CH);
  gemm_f32_kernel<<<dim3(CH / 128, NTOK / 64), 256, 0, stream>>>(x, wk, nullptr, kb, NTOK, CH, CH);
  gemm_f32_kernel<<<dim3(CH / 128, NTOK / 64), 256, 0, stream>>>(x, wv, nullptr, vb, NTOK, CH, CH);

  attn_kernel<<<dim3(BATCH * NHEAD, SEQ / 64), 256, 0, stream>>>(qb, kb, vb, ao);

  // o-proj + residual (fp32 exact): h2 = h + ao @ wo
  gemm_f32_kernel<<<dim3(CH / 128, NTOK / 64), 256, 0, stream>>>(ao, wo, h, h2, NTOK, CH, CH);

  ln2_kernel<<<NTOK, 256, 0, stream>>>(h2, g2, b2, out_x2, x2_bf);

  router_kernel<<<NTOK, 256, 0, stream>>>(out_x2, gate, out_rl, rw, sel, counts, lists);

  moe_fc1_bf16<<<dim3(FF / 128, NEXP, NTOK / 64), 256, 0, stream>>>(x2_bf, w1T, counts, lists, hidden);
  moe_fc2_bf16<<<dim3(CH / 128, NEXP, NTOK / 64), 256, 0, stream>>>(hidden, w2T, counts, lists, out_fe);

  combine_kernel<<<dim3(NTOK * CH / 1024), 256, 0, stream>>>(h2, out_fe, rw, sel, hf_bf);

  // logits = hf @ lm_head (bf16 MFMA, 4000 blocks %8==0 -> SWZ)
  gemm_bf16_kernel<1><<<dim3(VOCAB / 128, NTOK / 128), 256, 0, stream>>>(
      hf_bf, lmhT, out_logits, NTOK, VOCAB, CH);
}

// Round 7
// 1177.956 us; speedup vs baseline: 1.0725x; 1.0725x over previous
//
#include <hip/hip_runtime.h>
#include <hip/hip_bf16.h>

#define BATCH 4
#define SEQ   512
#define CH    512
#define NTOK  2048      // BATCH*SEQ
#define FF    2048      // I
#define NEXP  32
#define TOPK  2
#define VOCAB 32000
#define NHEAD 8
#define HDIM  64
#define EPSF  1e-5f

typedef __attribute__((ext_vector_type(8))) short short8v;   // 8 bf16 (4 VGPR)
typedef __attribute__((ext_vector_type(4))) float f32x4;     // MFMA acc

// async global->LDS, 16B per lane; LDS dest = wave-uniform base + lane*16
#define GLD16(g, lds) __builtin_amdgcn_global_load_lds(                      \
    (const __attribute__((address_space(1))) void*)(g),                      \
    (__attribute__((address_space(3))) void*)(lds), 16, 0, 0)

__device__ __forceinline__ unsigned short bf16r(float f) {   // RNE fp32->bf16
  unsigned int u = __float_as_uint(f);
  u = (u + 0x7FFFu + ((u >> 16) & 1u)) >> 16;
  return (unsigned short)u;
}

__device__ __forceinline__ float block_reduce_sum(float v, float* sbuf) {
  #pragma unroll
  for (int off = 32; off > 0; off >>= 1) v += __shfl_down(v, off, 64);
  const int lane = threadIdx.x & 63, wid = threadIdx.x >> 6;
  __syncthreads();
  if (lane == 0) sbuf[wid] = v;
  __syncthreads();
  return sbuf[0] + sbuf[1] + sbuf[2] + sbuf[3];
}

__device__ __forceinline__ float gelu_exact(float v) {
  return 0.5f * v * (1.f + erff(v * 0.70710678118654752f));
}

// ============ transpose + fp32->bf16 convert: out[c][r] = in[r][c] ============
__global__ __launch_bounds__(256) void transpose_cvt_kernel(
    const float* __restrict__ in, unsigned short* __restrict__ out, int R, int C) {
  __shared__ float T[64][65];
  const size_t zoff = (size_t)blockIdx.z * R * C;
  in += zoff; out += zoff;
  const int r0 = blockIdx.y << 6;
  const int c0 = blockIdx.x << 6;
  const int t = threadIdx.x;
  const int lr = t >> 4;            // 0..15
  const int lc = (t & 15) << 2;     // 0..60
  #pragma unroll
  for (int rr = 0; rr < 64; rr += 16) {
    const float4 v = *(const float4*)(in + (size_t)(r0 + lr + rr) * C + c0 + lc);
    T[lr + rr][lc + 0] = v.x; T[lr + rr][lc + 1] = v.y;
    T[lr + rr][lc + 2] = v.z; T[lr + rr][lc + 3] = v.w;
  }
  __syncthreads();
  const int oc = t >> 2;            // 0..63 output row (= input col)
  const int rs = (t & 3) << 4;      // 16-element segment along r
  unsigned int pk[8];
  #pragma unroll
  for (int j = 0; j < 8; ++j) {
    const float a = T[rs + 2 * j][oc];
    const float b = T[rs + 2 * j + 1][oc];
    pk[j] = (unsigned int)bf16r(a) | ((unsigned int)bf16r(b) << 16);
  }
  unsigned short* op = out + (size_t)(c0 + oc) * R + r0 + rs;
  *(uint4*)(op)     = make_uint4(pk[0], pk[1], pk[2], pk[3]);
  *(uint4*)(op + 8) = make_uint4(pk[4], pk[5], pk[6], pk[7]);
}

// ============ embed + LN1 -> h fp32, x fp32 ============
__global__ __launch_bounds__(256) void embed_ln_kernel(
    const int* __restrict__ ids, const float* __restrict__ emb,
    const float* __restrict__ g, const float* __restrict__ b,
    float* __restrict__ h, float* __restrict__ x) {
  __shared__ float sbuf[4];
  const int n = blockIdx.x, t = threadIdx.x;
  const float2 v = *(const float2*)(emb + (size_t)ids[n] * CH + 2 * t);
  *(float2*)(h + (size_t)n * CH + 2 * t) = v;
  const float mu = block_reduce_sum(v.x + v.y, sbuf) * (1.f / CH);
  const float d0 = v.x - mu, d1 = v.y - mu;
  const float var = block_reduce_sum(d0 * d0 + d1 * d1, sbuf) * (1.f / CH);
  const float rstd = rsqrtf(var + EPSF);
  const float2 gg = *(const float2*)(g + 2 * t);
  const float2 bb = *(const float2*)(b + 2 * t);
  *(float2*)(x + (size_t)n * CH + 2 * t) =
      make_float2(d0 * rstd * gg.x + bb.x, d1 * rstd * gg.y + bb.y);
}

// ============ LN2 -> x2 fp32 (output) + x2 bf16 (for MoE fc1) ============
__global__ __launch_bounds__(256) void ln2_kernel(
    const float* __restrict__ in, const float* __restrict__ g,
    const float* __restrict__ b, float* __restrict__ outf,
    unsigned short* __restrict__ outbf) {
  __shared__ float sbuf[4];
  const int n = blockIdx.x, t = threadIdx.x;
  const float2 v = *(const float2*)(in + (size_t)n * CH + 2 * t);
  const float mu = block_reduce_sum(v.x + v.y, sbuf) * (1.f / CH);
  const float d0 = v.x - mu, d1 = v.y - mu;
  const float var = block_reduce_sum(d0 * d0 + d1 * d1, sbuf) * (1.f / CH);
  const float rstd = rsqrtf(var + EPSF);
  const float2 gg = *(const float2*)(g + 2 * t);
  const float2 bb = *(const float2*)(b + 2 * t);
  const float o0 = d0 * rstd * gg.x + bb.x;
  const float o1 = d1 * rstd * gg.y + bb.y;
  *(float2*)(outf + (size_t)n * CH + 2 * t) = make_float2(o0, o1);
  ((unsigned int*)outbf)[(size_t)n * (CH / 2) + t] =
      (unsigned int)bf16r(o0) | ((unsigned int)bf16r(o1) << 16);
}

// ====== fused QKV fp32 GEMM (exact): z selects {wq,wk,wv} -> {qb,kb,vb} ======
// tile 64x128, BK=32, 256 threads, 4x8 micro-tile. grid (N/128, M/64, 3)
__global__ __launch_bounds__(256) void gemm_f32_qkv_kernel(
    const float* __restrict__ A,
    const float* __restrict__ Wq, const float* __restrict__ Wk,
    const float* __restrict__ Wv,
    float* __restrict__ Oq, float* __restrict__ Ok, float* __restrict__ Ov,
    int M, int N, int K) {
  const float* B = (blockIdx.z == 0) ? Wq : (blockIdx.z == 1) ? Wk : Wv;
  float*       C = (blockIdx.z == 0) ? Oq : (blockIdx.z == 1) ? Ok : Ov;
  __shared__ float As[32][68];
  __shared__ float Bs[32][132];
  const int m0 = blockIdx.y << 6;
  const int n0 = blockIdx.x << 7;
  const int t  = threadIdx.x;
  const int tm = t >> 4;
  const int tn = t & 15;
  float acc[4][8];
  #pragma unroll
  for (int i = 0; i < 4; ++i)
    #pragma unroll
    for (int j = 0; j < 8; ++j) acc[i][j] = 0.f;

  const int ar = t >> 3;          // 0..31
  const int ac = (t & 7) << 2;    // 0..28
  const int bk = t >> 3;          // 0..31
  const int bn = (t & 7) << 4;    // 0..112

  for (int kt = 0; kt < K; kt += 32) {
    #pragma unroll
    for (int rr = 0; rr < 64; rr += 32) {
      float4 a = *(const float4*)(A + (size_t)(m0 + ar + rr) * K + kt + ac);
      As[ac + 0][ar + rr] = a.x; As[ac + 1][ar + rr] = a.y;
      As[ac + 2][ar + rr] = a.z; As[ac + 3][ar + rr] = a.w;
    }
    const float* bp = B + (size_t)(kt + bk) * N + n0 + bn;
    #pragma unroll
    for (int j = 0; j < 16; j += 4)
      *(float4*)&Bs[bk][bn + j] = *(const float4*)(bp + j);
    __syncthreads();
    #pragma unroll
    for (int k = 0; k < 32; ++k) {
      const float4 av = *(const float4*)&As[k][tm << 2];
      const float4 bl = *(const float4*)&Bs[k][tn << 2];
      const float4 bh = *(const float4*)&Bs[k][64 + (tn << 2)];
      const float a_[4] = {av.x, av.y, av.z, av.w};
      const float b_[8] = {bl.x, bl.y, bl.z, bl.w, bh.x, bh.y, bh.z, bh.w};
      #pragma unroll
      for (int i = 0; i < 4; ++i)
        #pragma unroll
        for (int j = 0; j < 8; ++j)
          acc[i][j] = fmaf(a_[i], b_[j], acc[i][j]);
    }
    __syncthreads();
  }
  #pragma unroll
  for (int i = 0; i < 4; ++i) {
    const int row = m0 + (tm << 2) + i;
    float* cp = C + (size_t)row * N + n0 + (tn << 2);
    *(float4*)cp        = make_float4(acc[i][0], acc[i][1], acc[i][2], acc[i][3]);
    *(float4*)(cp + 64) = make_float4(acc[i][4], acc[i][5], acc[i][6], acc[i][7]);
  }
}

// ============ fp32 GEMM (exact routing path): C = A[M,K] @ B[K,N] (+Res) ======
__global__ __launch_bounds__(256) void gemm_f32_kernel(
    const float* __restrict__ A, const float* __restrict__ B,
    const float* __restrict__ Res, float* __restrict__ C,
    int M, int N, int K) {
  __shared__ float As[32][68];
  __shared__ float Bs[32][132];
  const int m0 = blockIdx.y << 6;
  const int n0 = blockIdx.x << 7;
  const int t  = threadIdx.x;
  const int tm = t >> 4;
  const int tn = t & 15;
  float acc[4][8];
  #pragma unroll
  for (int i = 0; i < 4; ++i)
    #pragma unroll
    for (int j = 0; j < 8; ++j) acc[i][j] = 0.f;

  const int ar = t >> 3;          // 0..31
  const int ac = (t & 7) << 2;    // 0..28
  const int bk = t >> 3;          // 0..31
  const int bn = (t & 7) << 4;    // 0..112

  for (int kt = 0; kt < K; kt += 32) {
    #pragma unroll
    for (int rr = 0; rr < 64; rr += 32) {
      float4 a = *(const float4*)(A + (size_t)(m0 + ar + rr) * K + kt + ac);
      As[ac + 0][ar + rr] = a.x; As[ac + 1][ar + rr] = a.y;
      As[ac + 2][ar + rr] = a.z; As[ac + 3][ar + rr] = a.w;
    }
    const float* bp = B + (size_t)(kt + bk) * N + n0 + bn;
    #pragma unroll
    for (int j = 0; j < 16; j += 4)
      *(float4*)&Bs[bk][bn + j] = *(const float4*)(bp + j);
    __syncthreads();
    #pragma unroll
    for (int k = 0; k < 32; ++k) {
      const float4 av = *(const float4*)&As[k][tm << 2];
      const float4 bl = *(const float4*)&Bs[k][tn << 2];
      const float4 bh = *(const float4*)&Bs[k][64 + (tn << 2)];
      const float a_[4] = {av.x, av.y, av.z, av.w};
      const float b_[8] = {bl.x, bl.y, bl.z, bl.w, bh.x, bh.y, bh.z, bh.w};
      #pragma unroll
      for (int i = 0; i < 4; ++i)
        #pragma unroll
        for (int j = 0; j < 8; ++j)
          acc[i][j] = fmaf(a_[i], b_[j], acc[i][j]);
    }
    __syncthreads();
  }
  #pragma unroll
  for (int i = 0; i < 4; ++i) {
    const int row = m0 + (tm << 2) + i;
    float* cp = C + (size_t)row * N + n0 + (tn << 2);
    float4 lo = make_float4(acc[i][0], acc[i][1], acc[i][2], acc[i][3]);
    float4 hi = make_float4(acc[i][4], acc[i][5], acc[i][6], acc[i][7]);
    if (Res) {
      const float* rp = Res + (size_t)row * N + n0 + (tn << 2);
      const float4 r0 = *(const float4*)rp;
      const float4 r1 = *(const float4*)(rp + 64);
      lo.x += r0.x; lo.y += r0.y; lo.z += r0.z; lo.w += r0.w;
      hi.x += r1.x; hi.y += r1.y; hi.z += r1.z; hi.w += r1.w;
    }
    *(float4*)cp        = lo;
    *(float4*)(cp + 64) = hi;
  }
}

// ============ bf16 MFMA GEMM (m97-style): C fp32 = A[M,K]bf16 @ BT[N,K]bf16 ====
// 128x128 tile, BK=64, 4 waves (2x2), 4x4 frags of 16x16x32.
// Staging via global_load_lds(16B) into LINEAR LDS [128][64] (wave-uniform base
// + lane*16 — no padding allowed). Two barriers per K-step.
template <int SWZ>
__global__ __launch_bounds__(256) void gemm_bf16_kernel(
    const unsigned short* __restrict__ A, const unsigned short* __restrict__ BT,
    float* __restrict__ C, int M, int N, int K) {
  int bx = blockIdx.x, by = blockIdx.y;
  if (SWZ) {
    const int gx = gridDim.x;
    const int nb = gx * gridDim.y;
    int bid = by * gx + bx;
    bid = (bid & 7) * (nb >> 3) + (bid >> 3);   // bijective when nb % 8 == 0
    bx = bid % gx;
    by = bid / gx;
  }
  __shared__ unsigned short As[128][64];
  __shared__ unsigned short Bs[128][64];
  const int m0 = by << 7;
  const int n0 = bx << 7;
  const int t  = threadIdx.x;
  const int w  = t >> 6;
  const int l  = t & 63;
  const int wm = (w >> 1) << 6;
  const int wn = (w & 1) << 6;
  const int fr = l & 15;
  const int fg = l >> 4;
  const int lrow = l >> 3;            // 0..7 within an 8-row group
  const int lcol = (l & 7) << 3;      // 0..56 bf16
  f32x4 acc[4][4];
  #pragma unroll
  for (int i = 0; i < 4; ++i)
    #pragma unroll
    for (int j = 0; j < 4; ++j) acc[i][j] = (f32x4){0.f, 0.f, 0.f, 0.f};

  for (int kt = 0; kt < K; kt += 64) {
    #pragma unroll
    for (int q = 0; q < 4; ++q) {
      const int r = (w << 5) + (q << 3);        // wave fills rows [w*32, w*32+32)
      GLD16(A  + (size_t)(m0 + r + lrow) * K + kt + lcol, &As[r][0]);
      GLD16(BT + (size_t)(n0 + r + lrow) * K + kt + lcol, &Bs[r][0]);
    }
    __syncthreads();                            // drains vmcnt (compiler-emitted)
    #pragma unroll
    for (int kk = 0; kk < 64; kk += 32) {
      short8v afr[4], bfr[4];
      #pragma unroll
      for (int i = 0; i < 4; ++i)
        afr[i] = *(const short8v*)&As[wm + (i << 4) + fr][kk + (fg << 3)];
      #pragma unroll
      for (int j = 0; j < 4; ++j)
        bfr[j] = *(const short8v*)&Bs[wn + (j << 4) + fr][kk + (fg << 3)];
      #pragma unroll
      for (int i = 0; i < 4; ++i)
        #pragma unroll
        for (int j = 0; j < 4; ++j)
          acc[i][j] = __builtin_amdgcn_mfma_f32_16x16x32_bf16(afr[i], bfr[j], acc[i][j], 0, 0, 0);
    }
    __syncthreads();
  }
  #pragma unroll
  for (int i = 0; i < 4; ++i) {
    #pragma unroll
    for (int j = 0; j < 4; ++j) {
      const int col = n0 + wn + (j << 4) + fr;
      const int rowb = m0 + wm + (i << 4) + (fg << 2);
      #pragma unroll
      for (int r = 0; r < 4; ++r)
        C[(size_t)(rowb + r) * N + col] = acc[i][j][r];
    }
  }
}

// ============ flash attention fp32 (exact routing path), separate q/k/v ======
__global__ __launch_bounds__(256) void attn_kernel(
    const float* __restrict__ q, const float* __restrict__ kbuf,
    const float* __restrict__ vbuf, float* __restrict__ ao) {
  __shared__ float Ks[64][68];
  __shared__ float Vs[64][68];
  __shared__ float Sx[64][65];
  const int bh = blockIdx.x;
  const int qt = blockIdx.y;
  const int b  = bh >> 3;
  const int hh = bh & 7;
  const int t  = threadIdx.x;
  const int qi   = t >> 2;
  const int part = t & 3;
  const int qglob = (qt << 6) + qi;
  const size_t qoff = (size_t)(b * SEQ + qglob) * CH + hh * HDIM + (part << 4);
  float qreg[16];
  #pragma unroll
  for (int j = 0; j < 16; j += 4) {
    const float4 v4 = *(const float4*)(q + qoff + j);
    qreg[j] = v4.x; qreg[j + 1] = v4.y; qreg[j + 2] = v4.z; qreg[j + 3] = v4.w;
  }
  float o[16];
  #pragma unroll
  for (int j = 0; j < 16; ++j) o[j] = 0.f;
  float m = -3.0e38f, l = 0.f;
  const int lr = t >> 2;
  const int lc = (t & 3) << 4;
  for (int kt = 0; kt <= qt; ++kt) {
    const size_t base = (size_t)(b * SEQ + (kt << 6) + lr) * CH + hh * HDIM + lc;
    #pragma unroll
    for (int j = 0; j < 16; j += 4) {
      *(float4*)&Ks[lr][lc + j] = *(const float4*)(kbuf + base + j);
      *(float4*)&Vs[lr][lc + j] = *(const float4*)(vbuf + base + j);
    }
    __syncthreads();
    float sloc[16];
    float tmax = -3.0e38f;
    for (int kk = 0; kk < 64; ++kk) {
      float p = 0.f;
      const float* kr = &Ks[kk][part << 4];
      #pragma unroll
      for (int j = 0; j < 16; ++j) p = fmaf(qreg[j], kr[j], p);
      p += __shfl_xor(p, 1, 64);
      p += __shfl_xor(p, 2, 64);
      p *= 0.125f;
      if (((kt << 6) + kk) > qglob) p = -3.0e38f;
      tmax = fmaxf(tmax, p);
      if ((kk & 3) == part) sloc[kk >> 2] = p;
    }
    const float mnew = fmaxf(m, tmax);
    const float corr = expf(m - mnew);
    float lsum = 0.f;
    #pragma unroll
    for (int j = 0; j < 16; ++j) {
      const float pe = expf(sloc[j] - mnew);
      lsum += pe;
      Sx[qi][(j << 2) + part] = pe;
    }
    lsum += __shfl_xor(lsum, 1, 64);
    lsum += __shfl_xor(lsum, 2, 64);
    l = l * corr + lsum;
    m = mnew;
    #pragma unroll
    for (int j = 0; j < 16; ++j) o[j] *= corr;
    __syncthreads();
    for (int kk = 0; kk < 64; ++kk) {
      const float pv = Sx[qi][kk];
      const float* vr = &Vs[kk][part << 4];
      #pragma unroll
      for (int j = 0; j < 16; ++j) o[j] = fmaf(pv, vr[j], o[j]);
    }
    __syncthreads();
  }
  const float inv = 1.f / l;
  #pragma unroll
  for (int j = 0; j < 16; j += 4)
    *(float4*)(ao + qoff + j) =
        make_float4(o[j] * inv, o[j + 1] * inv, o[j + 2] * inv, o[j + 3] * inv);
}

// ============ router + top-2 + bucketing (fp32, exact) ============
__global__ __launch_bounds__(256) void router_kernel(
    const float* __restrict__ x2, const float* __restrict__ gate,
    float* __restrict__ rl, float* __restrict__ rw, int* __restrict__ sel,
    int* __restrict__ counts, int* __restrict__ lists) {
  __shared__ float xrow[CH];
  __shared__ float lg[NEXP];
  const int n = blockIdx.x;
  const int t = threadIdx.x;
  xrow[t]       = x2[(size_t)n * CH + t];
  xrow[t + 256] = x2[(size_t)n * CH + t + 256];
  __syncthreads();
  const int e = t >> 3, i = t & 7;
  float p = 0.f;
  const float* gp = gate + e;
  for (int c = i * 64; c < i * 64 + 64; ++c) p = fmaf(xrow[c], gp[(size_t)c * NEXP], p);
  p += __shfl_xor(p, 1, 64);
  p += __shfl_xor(p, 2, 64);
  p += __shfl_xor(p, 4, 64);
  if (i == 0) { lg[e] = p; rl[(size_t)n * NEXP + e] = p; }
  __syncthreads();
  if (t == 0) {
    int i0 = 0; float v0 = lg[0];
    for (int j = 1; j < NEXP; ++j) if (lg[j] > v0) { v0 = lg[j]; i0 = j; }
    int i1 = (i0 == 0) ? 1 : 0; float v1 = lg[i1];
    for (int j = 0; j < NEXP; ++j) {
      if (j == i0 || j == i1) continue;
      if (lg[j] > v1) { v1 = lg[j]; i1 = j; }
    }
    const float ex = expf(v1 - v0);
    const float den = 1.f + ex;
    rw[n * 2]     = 1.f / den;
    rw[n * 2 + 1] = ex / den;
    sel[n * 2]     = i0;
    sel[n * 2 + 1] = i1;
    const int s0 = atomicAdd(&counts[i0], 1);
    lists[i0 * NTOK + s0] = n * 2;
    const int s1 = atomicAdd(&counts[i1], 1);
    lists[i1 * NTOK + s1] = n * 2 + 1;
  }
}

// ============ MoE fc1: hidden[pid] = bf16(gelu(x2 @ w1[e])) ============
// tile 64 tok x 128 ff, BK=64. A: ds_write staging (gather); B: global_load_lds.
__global__ __launch_bounds__(256) void moe_fc1_bf16(
    const unsigned short* __restrict__ x2bf, const unsigned short* __restrict__ w1T,
    const int* __restrict__ counts, const int* __restrict__ lists,
    unsigned short* __restrict__ hidden) {
  const int e  = blockIdx.y;
  const int nt = counts[e];
  const int mt = blockIdx.z << 6;
  if (mt >= nt) return;
  const int i0 = blockIdx.x << 7;
  __shared__ unsigned short As[64][72];
  __shared__ unsigned short Bs[128][64];
  __shared__ int ls[64];
  const int* lst = lists + e * NTOK;
  const int t = threadIdx.x;
  if (t < 64) ls[t] = (mt + t < nt) ? lst[mt + t] : -1;
  __syncthreads();
  const int w  = t >> 6, l = t & 63;
  const int wm = (w >> 1) << 5;       // 0 or 32
  const int wn = (w & 1) << 6;        // 0 or 64
  const int fr = l & 15, fg = l >> 4;
  const int lrow = l >> 3, lcol = (l & 7) << 3;
  f32x4 acc[2][4];
  #pragma unroll
  for (int i = 0; i < 2; ++i)
    #pragma unroll
    for (int j = 0; j < 4; ++j) acc[i][j] = (f32x4){0.f, 0.f, 0.f, 0.f};

  const int arow = t >> 2, akc = (t & 3) << 4;      // A: 64 rows x 32B
  const int apid = ls[arow];
  const unsigned short* arp = (apid >= 0) ? (x2bf + (size_t)(apid >> 1) * CH) : nullptr;
  const unsigned short* w1e = w1T + (size_t)e * FF * CH;

  for (int kt = 0; kt < CH; kt += 64) {
    if (arp) {
      *(uint4*)&As[arow][akc + 0] = *(const uint4*)(arp + kt + akc + 0);
      *(uint4*)&As[arow][akc + 8] = *(const uint4*)(arp + kt + akc + 8);
    } else {
      *(uint4*)&As[arow][akc + 0] = make_uint4(0, 0, 0, 0);
      *(uint4*)&As[arow][akc + 8] = make_uint4(0, 0, 0, 0);
    }
    #pragma unroll
    for (int q = 0; q < 4; ++q) {
      const int r = (w << 5) + (q << 3);
      GLD16(w1e + (size_t)(i0 + r + lrow) * CH + kt + lcol, &Bs[r][0]);
    }
    __syncthreads();
    #pragma unroll
    for (int kk = 0; kk < 64; kk += 32) {
      short8v afr[2], bfr[4];
      #pragma unroll
      for (int i = 0; i < 2; ++i)
        afr[i] = *(const short8v*)&As[wm + (i << 4) + fr][kk + (fg << 3)];
      #pragma unroll
      for (int j = 0; j < 4; ++j)
        bfr[j] = *(const short8v*)&Bs[wn + (j << 4) + fr][kk + (fg << 3)];
      #pragma unroll
      for (int i = 0; i < 2; ++i)
        #pragma unroll
        for (int j = 0; j < 4; ++j)
          acc[i][j] = __builtin_amdgcn_mfma_f32_16x16x32_bf16(afr[i], bfr[j], acc[i][j], 0, 0, 0);
    }
    __syncthreads();
  }
  #pragma unroll
  for (int i = 0; i < 2; ++i) {
    #pragma unroll
    for (int r = 0; r < 4; ++r) {
      const int lrow2 = wm + (i << 4) + (fg << 2) + r;
      const int pid = ls[lrow2];
      if (pid < 0) continue;
      unsigned short* hp = hidden + (size_t)pid * FF + i0 + wn + fr;
      #pragma unroll
      for (int j = 0; j < 4; ++j)
        hp[j << 4] = bf16r(gelu_exact(acc[i][j][r]));
    }
  }
}

// ============ MoE fc2: fe[n,e] = hidden[pid] @ w2[e] (fp32 out) ============
__global__ __launch_bounds__(256) void moe_fc2_bf16(
    const unsigned short* __restrict__ hidden, const unsigned short* __restrict__ w2T,
    const int* __restrict__ counts, const int* __restrict__ lists,
    float* __restrict__ fe) {
  const int e  = blockIdx.y;
  const int nt = counts[e];
  const int mt = blockIdx.z << 6;
  if (mt >= nt) return;
  const int c0 = blockIdx.x << 7;
  __shared__ unsigned short As[64][72];
  __shared__ unsigned short Bs[128][64];
  __shared__ int ls[64];
  const int* lst = lists + e * NTOK;
  const int t = threadIdx.x;
  if (t < 64) ls[t] = (mt + t < nt) ? lst[mt + t] : -1;
  __syncthreads();
  const int w  = t >> 6, l = t & 63;
  const int wm = (w >> 1) << 5;
  const int wn = (w & 1) << 6;
  const int fr = l & 15, fg = l >> 4;
  const int lrow = l >> 3, lcol = (l & 7) << 3;
  f32x4 acc[2][4];
  #pragma unroll
  for (int i = 0; i < 2; ++i)
    #pragma unroll
    for (int j = 0; j < 4; ++j) acc[i][j] = (f32x4){0.f, 0.f, 0.f, 0.f};

  const int arow = t >> 2, akc = (t & 3) << 4;
  const int apid = ls[arow];
  const unsigned short* arp = (apid >= 0) ? (hidden + (size_t)apid * FF) : nullptr;
  const unsigned short* w2e = w2T + (size_t)e * CH * FF;

  for (int kt = 0; kt < FF; kt += 64) {
    if (arp) {
      *(uint4*)&As[arow][akc + 0] = *(const uint4*)(arp + kt + akc + 0);
      *(uint4*)&As[arow][akc + 8] = *(const uint4*)(arp + kt + akc + 8);
    } else {
      *(uint4*)&As[arow][akc + 0] = make_uint4(0, 0, 0, 0);
      *(uint4*)&As[arow][akc + 8] = make_uint4(0, 0, 0, 0);
    }
    #pragma unroll
    for (int q = 0; q < 4; ++q) {
      const int r = (w << 5) + (q << 3);
      GLD16(w2e + (size_t)(c0 + r + lrow) * FF + kt + lcol, &Bs[r][0]);
    }
    __syncthreads();
    #pragma unroll
    for (int kk = 0; kk < 64; kk += 32) {
      short8v afr[2], bfr[4];
      #pragma unroll
      for (int i = 0; i < 2; ++i)
        afr[i] = *(const short8v*)&As[wm + (i << 4) + fr][kk + (fg << 3)];
      #pragma unroll
      for (int j = 0; j < 4; ++j)
        bfr[j] = *(const short8v*)&Bs[wn + (j << 4) + fr][kk + (fg << 3)];
      #pragma unroll
      for (int i = 0; i < 2; ++i)
        #pragma unroll
        for (int j = 0; j < 4; ++j)
          acc[i][j] = __builtin_amdgcn_mfma_f32_16x16x32_bf16(afr[i], bfr[j], acc[i][j], 0, 0, 0);
    }
    __syncthreads();
  }
  #pragma unroll
  for (int i = 0; i < 2; ++i) {
    #pragma unroll
    for (int r = 0; r < 4; ++r) {
      const int lrow2 = wm + (i << 4) + (fg << 2) + r;
      const int pid = ls[lrow2];
      if (pid < 0) continue;
      const int n = pid >> 1;
      float* op = fe + ((size_t)n * NEXP + e) * CH + c0 + wn + fr;
      #pragma unroll
      for (int j = 0; j < 4; ++j)
        op[j << 4] = acc[i][j][r];
    }
  }
}

// ============ combine: hf_bf = bf16(h2 + rw0*fe[s0] + rw1*fe[s1]) ============
__global__ __launch_bounds__(256) void combine_kernel(
    const float* __restrict__ h2, const float* __restrict__ fe,
    const float* __restrict__ rw, const int* __restrict__ sel,
    unsigned short* __restrict__ hfbf) {
  const int idx = blockIdx.x * 256 + threadIdx.x;   // NTOK*CH/4
  const int n = idx >> 7;
  const int c = (idx & 127) << 2;
  const float w0 = rw[n * 2], w1 = rw[n * 2 + 1];
  const int s0 = sel[n * 2], s1 = sel[n * 2 + 1];
  const float* base = fe + (size_t)n * NEXP * CH + c;
  const float4 f0 = *(const float4*)(base + (size_t)s0 * CH);
  const float4 f1 = *(const float4*)(base + (size_t)s1 * CH);
  const float4 a  = *(const float4*)(h2 + (size_t)n * CH + c);
  const float ox = a.x + w0 * f0.x + w1 * f1.x;
  const float oy = a.y + w0 * f0.y + w1 * f1.y;
  const float oz = a.z + w0 * f0.z + w1 * f1.z;
  const float ow = a.w + w0 * f0.w + w1 * f1.w;
  uint2 pk;
  pk.x = (unsigned int)bf16r(ox) | ((unsigned int)bf16r(oy) << 16);
  pk.y = (unsigned int)bf16r(oz) | ((unsigned int)bf16r(ow) << 16);
  *(uint2*)(hfbf + (size_t)n * CH + c) = pk;
}

// ============ launch ============
extern "C" void kernel_launch(void* const* d_in, const int* in_sizes, int n_in,
                              void* d_out, int out_size, void* d_ws, size_t ws_size,
                              hipStream_t stream) {
  const int*   ids  = (const int*)d_in[0];
  const float* emb  = (const float*)d_in[1];
  const float* wq   = (const float*)d_in[2];
  const float* wk   = (const float*)d_in[3];
  const float* wv   = (const float*)d_in[4];
  const float* wo   = (const float*)d_in[5];
  const float* gate = (const float*)d_in[6];
  const float* w1   = (const float*)d_in[7];
  const float* w2   = (const float*)d_in[8];
  const float* g1   = (const float*)d_in[9];
  const float* b1   = (const float*)d_in[10];
  const float* g2   = (const float*)d_in[11];
  const float* b2   = (const float*)d_in[12];
  const float* lmh  = (const float*)d_in[13];

  float* out        = (float*)d_out;
  float* out_logits = out;                                   // 65,536,000 f
  float* out_fe     = out_logits + (size_t)NTOK * VOCAB;     // 33,554,432 f
  float* out_rl     = out_fe + (size_t)NTOK * NEXP * CH;     // 65,536 f
  float* out_x2     = out_rl + (size_t)NTOK * NEXP;          // 1,048,576 f

  // --- scratch inside out_logits region: all DEAD before final GEMM writes ---
  unsigned short* w1T    = (unsigned short*)(out_logits);                // [0, 16,777,216) f
  unsigned short* w2T    = (unsigned short*)(out_logits + 16777216);     // [.., 33,554,432)
  unsigned short* hidden = (unsigned short*)(out_logits + 33554432);     // [.., 37,748,736)
  float*          x      = out_logits + 37748736;                        // [.., 38,797,312)
  float*          qb     = out_logits + 38797312;                        // [.., 39,845,888)
  float*          kb     = out_logits + 39845888;                        // [.., 40,894,464)
  float*          vb     = out_logits + 40894464;                        // [.., 41,943,040)
  float*          ao     = out_logits + 41943040;                        // [.., 42,991,616)
  float*          h      = out_logits + 42991616;                        // [.., 44,040,192)
  float*          h2     = out_logits + 44040192;                        // [.., 45,088,768)
  unsigned short* x2_bf  = (unsigned short*)(out_logits + 45088768);     // [.., 45,613,056)
  // ends at 45,613,056 f < 65,536,000 f

  // --- ws: ONLY what the final GEMM reads + bucketing smalls (~35.2 MB) ---
  float* ws    = (float*)d_ws;
  unsigned short* lmhT  = (unsigned short*)ws;               // 16,384,000 bf16 = 8,192,000 f
  unsigned short* hf_bf = (unsigned short*)(ws + 8192000);   // 1,048,576 bf16 = 524,288 f
  float* rw    = ws + 8716288;
  int*   sel   = (int*)(rw + NTOK * TOPK);
  int*   counts= sel + NTOK * TOPK;
  int*   lists = counts + 64;                                // NEXP*NTOK ints

  hipMemsetAsync(counts, 0, NEXP * sizeof(int), stream);
  hipMemsetAsync(out_fe, 0, (size_t)NTOK * NEXP * CH * sizeof(float), stream);

  // weight transposes (fp32 -> bf16 [N][K]) — only MoE + lm_head need them
  transpose_cvt_kernel<<<dim3(500, 8, 1),   256, 0, stream>>>(lmh, lmhT, CH, VOCAB);
  transpose_cvt_kernel<<<dim3(32, 8, NEXP), 256, 0, stream>>>(w1, w1T, CH, FF);
  transpose_cvt_kernel<<<dim3(8, 32, NEXP), 256, 0, stream>>>(w2, w2T, FF, CH);

  embed_ln_kernel<<<NTOK, 256, 0, stream>>>(ids, emb, g1, b1, h, x);

  // QKV projections (fp32 exact, fused into one launch via blockIdx.z)
  gemm_f32_qkv_kernel<<<dim3(CH / 128, NTOK / 64, 3), 256, 0, stream>>>(
      x, wq, wk, wv, qb, kb, vb, NTOK, CH, CH);

  attn_kernel<<<dim3(BATCH * NHEAD, SEQ / 64), 256, 0, stream>>>(qb, kb, vb, ao);

  // o-proj + residual (fp32 exact): h2 = h + ao @ wo
  gemm_f32_kernel<<<dim3(CH / 128, NTOK / 64), 256, 0, stream>>>(ao, wo, h, h2, NTOK, CH, CH);

  ln2_kernel<<<NTOK, 256, 0, stream>>>(h2, g2, b2, out_x2, x2_bf);

  router_kernel<<<NTOK, 256, 0, stream>>>(out_x2, gate, out_rl, rw, sel, counts, lists);

  moe_fc1_bf16<<<dim3(FF / 128, NEXP, NTOK / 64), 256, 0, stream>>>(x2_bf, w1T, counts, lists, hidden);
  moe_fc2_bf16<<<dim3(CH / 128, NEXP, NTOK / 64), 256, 0, stream>>>(hidden, w2T, counts, lists, out_fe);

  combine_kernel<<<dim3(NTOK * CH / 1024), 256, 0, stream>>>(h2, out_fe, rw, sel, hf_bf);

  // logits = hf @ lm_head (bf16 MFMA m97-style, 4000 blocks %8==0 -> SWZ)
  gemm_bf16_kernel<1><<<dim3(VOCAB / 128, NTOK / 128), 256, 0, stream>>>(
      hf_bf, lmhT, out_logits, NTOK, VOCAB, CH);
}